// Round 1
// baseline (189560.498 us; speedup 1.0000x reference)
//
#include <hip/hip_runtime.h>
#include <math.h>

#define B_   32
#define INS  1000
#define TS   999           // recurrent steps computed (t = 0..998)
#define D_   128
#define U_   512
#define G3   1536
#define OUTS 100
#define NB   208           // persistent grid: 16 LX + 64 L0 + 64 L1 + 64 L2
#define NTICK 1002         // LX: T=t (0..998); layer j computes t = T-(j+1)

// ws layout (floats)
#define HBUF_OFF 0                       // [2][3][512][32]  (parity, layer, k, e)
#define HBUF_SZ  (2*3*512*32)            // 98304
#define RING_OFF HBUF_SZ                 // [4][1536][32]    mx0 ring
#define RING_SZ  (4*1536*32)             // 196608
#define BAR_OFF  (RING_OFF + RING_SZ)    // 2 x u32 barrier state

#define PIDX(q,c,g,e) ((((q)*8 + (c))*3 + (g))*32 + (e))

__global__ void gru_init_kernel(const float* __restrict__ s0,
                                const float* __restrict__ s1,
                                const float* __restrict__ s2,
                                float* __restrict__ ws) {
  int g = blockIdx.x * 256 + threadIdx.x;
  if (g < 2) { unsigned* bar = (unsigned*)(ws + BAR_OFF); bar[g] = 0u; }
  // init h(-1): hbuf[0][0]=s0, hbuf[1][1]=s1, hbuf[0][2]=s2
  for (int i = g; i < 3 * 512 * 32; i += gridDim.x * 256) {
    int which = i / (512 * 32);
    int r = i - which * (512 * 32);
    int k = r >> 5, e = r & 31;
    int par = (which == 1) ? 1 : 0;
    const float* s = (which == 0) ? s0 : ((which == 1) ? s1 : s2);
    ws[HBUF_OFF + par * 49152 + which * 16384 + k * 32 + e] = s[k];
  }
}

__device__ __forceinline__ void gbar(unsigned* bar, unsigned ep) {
  __syncthreads();
  if (threadIdx.x == 0) {
    __threadfence();
    unsigned prev = __hip_atomic_fetch_add(&bar[0], 1u, __ATOMIC_ACQ_REL,
                                           __HIP_MEMORY_SCOPE_AGENT);
    if (prev == ep * (unsigned)NB - 1u) {
      __hip_atomic_store(&bar[1], ep, __ATOMIC_RELEASE, __HIP_MEMORY_SCOPE_AGENT);
    } else {
      unsigned cur;
      do {
        __builtin_amdgcn_s_sleep(2);
        cur = __hip_atomic_load(&bar[1], __ATOMIC_ACQUIRE, __HIP_MEMORY_SCOPE_AGENT);
      } while (cur < ep);
    }
    __threadfence();
  }
  __syncthreads();
}

__global__ __launch_bounds__(256, 1) void gru_persist(
    const float* __restrict__ x,
    const float* __restrict__ W0c, const float* __restrict__ U0c, const float* __restrict__ b0c,
    const float* __restrict__ W1c, const float* __restrict__ U1c, const float* __restrict__ b1c,
    const float* __restrict__ W2c, const float* __restrict__ U2c, const float* __restrict__ b2c,
    const float* __restrict__ Wd, const float* __restrict__ bd,
    float* __restrict__ out, float* __restrict__ ws)
{
  float* hbuf = ws + HBUF_OFF;
  float* ring = ws + RING_OFF;
  unsigned* bar = (unsigned*)(ws + BAR_OFF);
  float* pred_out = out;                       // [32][100][128]
  float* hid_out  = out + B_ * OUTS * D_;      // [32][100][3][512]

  const int bid = blockIdx.x;
  const int tid = threadIdx.x;

  // roles: bid 0..15 LX, 16..79 layer0, 80..143 layer1, 144..207 layer2
  int role, rb;
  if      (bid < 16)  { role = -1; rb = bid; }
  else if (bid < 80)  { role = 0;  rb = bid - 16; }
  else if (bid < 144) { role = 1;  rb = bid - 80; }
  else                { role = 2;  rb = bid - 144; }

  __shared__ float part[8 * 8 * 3 * 32];   // [q][c][g][e] = 24 KiB

  // GEMM-phase thread mapping: c_l 0..7, q 0..7 (k-chunk), eg 0..3 (8 elems)
  const int c_l = tid & 7;
  const int q   = (tid >> 3) & 7;
  const int eg  = tid >> 6;
  // XCD-locality col swizzle: same-XCD blocks (rb = const mod 8) get adjacent cols
  const int cb  = (rb & 7) * 8 + (rb >> 3);
  const int c0  = cb * 8;
  const int gc  = c0 + c_l;
  // reduce/elementwise mapping
  const int rc = tid >> 5;     // col within block 0..7
  const int re = tid & 31;     // batch elem 0..31

  const float *Wj = nullptr, *Ujp = nullptr, *bj = nullptr;
  if      (role == 0) { Ujp = U0c; bj = b0c; }
  else if (role == 1) { Wj = W1c; Ujp = U1c; bj = b1c; }
  else if (role == 2) { Wj = W2c; Ujp = U2c; bj = b2c; }

  for (int T = 0; T < NTICK; ++T) {
    const int par_prev = (T + 1) & 1;
    const int par_cur  = T & 1;

    if (role < 0) {
      // LX: mx0(t=T) = x_t @ W0  (no bias), into ring slot t&3, layout [gc][e]
      const int t = T;
      if (t < TS) {
        float* dst = ring + (t & 3) * (G3 * 32);
        const int xb0 = ((rb & 7) * 2 + (rb >> 3)) * 96;   // swizzled col range
        for (int it = tid; it < 96 * 32; it += 256) {
          int e = it / 96;
          int gcl = it - e * 96;
          int g = xb0 + gcl;
          const float* xr = x + (e * INS + t) * D_;
          const float* wc = W0c + g;
          float acc = 0.f;
          #pragma unroll 4
          for (int k = 0; k < D_; k += 4) {
            float4 xv = *(const float4*)(xr + k);
            acc = fmaf(xv.x, wc[(k    ) * G3], acc);
            acc = fmaf(xv.y, wc[(k + 1) * G3], acc);
            acc = fmaf(xv.z, wc[(k + 2) * G3], acc);
            acc = fmaf(xv.w, wc[(k + 3) * G3], acc);
          }
          dst[g * 32 + e] = acc;
        }
      }
    } else {
      const int j = role;
      const int t = T - (j + 1);
      if (t >= 0 && t < TS) {
        const float* hprev_all = hbuf + par_prev * 49152;
        float acc[3][8];
        #pragma unroll
        for (int g2 = 0; g2 < 3; ++g2)
          #pragma unroll
          for (int i2 = 0; i2 < 8; ++i2) acc[g2][i2] = 0.f;

        const float* A; const float* Wcol; int chunk;
        if (j == 0) {
          chunk = 64;                                   // K=512 over U0 only
          A    = hprev_all + 0 * 16384 + (q * 64) * 32 + eg * 8;
          Wcol = Ujp + (q * 64) * G3 + gc;
        } else {
          chunk = 128;                                  // K=1024 = [inp(512)|h(512)]
          const int kb = (q & 3) * 128;
          const bool xside = (q < 4);
          A    = hprev_all + (xside ? (j - 1) : j) * 16384 + kb * 32 + eg * 8;
          Wcol = (xside ? Wj : Ujp) + kb * G3 + gc;
        }
        #pragma unroll 2
        for (int i = 0; i < chunk; ++i) {
          const float4 a0 = *(const float4*)(A);
          const float4 a1 = *(const float4*)(A + 4);
          const float w0 = Wcol[0];
          const float w1 = Wcol[512];
          const float w2 = Wcol[1024];
          acc[0][0] = fmaf(a0.x, w0, acc[0][0]);
          acc[0][1] = fmaf(a0.y, w0, acc[0][1]);
          acc[0][2] = fmaf(a0.z, w0, acc[0][2]);
          acc[0][3] = fmaf(a0.w, w0, acc[0][3]);
          acc[0][4] = fmaf(a1.x, w0, acc[0][4]);
          acc[0][5] = fmaf(a1.y, w0, acc[0][5]);
          acc[0][6] = fmaf(a1.z, w0, acc[0][6]);
          acc[0][7] = fmaf(a1.w, w0, acc[0][7]);
          acc[1][0] = fmaf(a0.x, w1, acc[1][0]);
          acc[1][1] = fmaf(a0.y, w1, acc[1][1]);
          acc[1][2] = fmaf(a0.z, w1, acc[1][2]);
          acc[1][3] = fmaf(a0.w, w1, acc[1][3]);
          acc[1][4] = fmaf(a1.x, w1, acc[1][4]);
          acc[1][5] = fmaf(a1.y, w1, acc[1][5]);
          acc[1][6] = fmaf(a1.z, w1, acc[1][6]);
          acc[1][7] = fmaf(a1.w, w1, acc[1][7]);
          acc[2][0] = fmaf(a0.x, w2, acc[2][0]);
          acc[2][1] = fmaf(a0.y, w2, acc[2][1]);
          acc[2][2] = fmaf(a0.z, w2, acc[2][2]);
          acc[2][3] = fmaf(a0.w, w2, acc[2][3]);
          acc[2][4] = fmaf(a1.x, w2, acc[2][4]);
          acc[2][5] = fmaf(a1.y, w2, acc[2][5]);
          acc[2][6] = fmaf(a1.z, w2, acc[2][6]);
          acc[2][7] = fmaf(a1.w, w2, acc[2][7]);
          A += 32; Wcol += G3;
        }
        #pragma unroll
        for (int g2 = 0; g2 < 3; ++g2) {
          float* basep = &part[PIDX(q, c_l, g2, eg * 8)];
          *(float4*)(basep)     = make_float4(acc[g2][0], acc[g2][1], acc[g2][2], acc[g2][3]);
          *(float4*)(basep + 4) = make_float4(acc[g2][4], acc[g2][5], acc[g2][6], acc[g2][7]);
        }
        __syncthreads();

        // reduce over q + GRU elementwise; thread <-> (rc, re)
        float gz = 0.f, gr = 0.f, xh = 0.f, hh = 0.f;
        #pragma unroll
        for (int q2 = 0; q2 < 8; ++q2) {
          gz += part[PIDX(q2, rc, 0, re)];
          gr += part[PIDX(q2, rc, 1, re)];
          float v = part[PIDX(q2, rc, 2, re)];
          if (j == 0)       hh += v;
          else if (q2 < 4)  xh += v;
          else              hh += v;
        }
        const int cg2 = c0 + rc;
        const float b0z = bj[cg2],        b1z = bj[G3 + cg2];
        const float b0r = bj[512 + cg2],  b1r = bj[G3 + 512 + cg2];
        const float b0h = bj[1024 + cg2], b1h = bj[G3 + 1024 + cg2];
        float xz = 0.f, xr2 = 0.f, xhv;
        if (j == 0) {
          const float* r3 = ring + (t & 3) * (G3 * 32);
          xz  = r3[cg2 * 32 + re];
          xr2 = r3[(512 + cg2) * 32 + re];
          xhv = r3[(1024 + cg2) * 32 + re];
        } else {
          xhv = xh;
        }
        const float zi = gz + xz + b0z + b1z;
        const float ri = gr + xr2 + b0r + b1r;
        const float z = 1.f / (1.f + expf(-zi));
        const float r = 1.f / (1.f + expf(-ri));
        const float cand = tanhf((xhv + b0h) + r * (hh + b1h));
        const float hp = hbuf[par_prev * 49152 + j * 16384 + cg2 * 32 + re];
        const float hn = z * hp + (1.f - z) * cand;
        hbuf[par_cur * 49152 + j * 16384 + cg2 * 32 + re] = hn;
        if (t >= TS - OUTS) {
          hid_out[((re * OUTS + (t - (TS - OUTS))) * 3 + j) * U_ + cg2] = hn;
        }
      }
      // inactive ticks fall through to barrier
    }
    gbar(bar, (unsigned)(T + 1));
  }

  // readout: pred[b][s][dd] = ys[b][s] @ Wd + bd   (ys = hidden[...,2,:])
  const int gt = bid * 256 + tid;
  for (int o = gt; o < B_ * OUTS * D_; o += NB * 256) {
    int b  = o / (OUTS * D_);
    int r2 = o - b * (OUTS * D_);
    int s  = r2 >> 7;
    int dd = r2 & 127;
    const float* ys = hid_out + ((b * OUTS + s) * 3 + 2) * U_;
    float acc = bd[dd];
    #pragma unroll 4
    for (int k = 0; k < U_; k += 4) {
      float4 yv = *(const float4*)(ys + k);
      acc = fmaf(yv.x, Wd[(k    ) * D_ + dd], acc);
      acc = fmaf(yv.y, Wd[(k + 1) * D_ + dd], acc);
      acc = fmaf(yv.z, Wd[(k + 2) * D_ + dd], acc);
      acc = fmaf(yv.w, Wd[(k + 3) * D_ + dd], acc);
    }
    pred_out[o] = acc;
  }
}

extern "C" void kernel_launch(void* const* d_in, const int* in_sizes, int n_in,
                              void* d_out, int out_size, void* d_ws, size_t ws_size,
                              hipStream_t stream) {
  const float* x  = (const float*)d_in[0];
  const float* W0 = (const float*)d_in[1];
  const float* U0 = (const float*)d_in[2];
  const float* b0 = (const float*)d_in[3];
  const float* s0 = (const float*)d_in[4];
  const float* W1 = (const float*)d_in[5];
  const float* U1 = (const float*)d_in[6];
  const float* b1 = (const float*)d_in[7];
  const float* s1 = (const float*)d_in[8];
  const float* W2 = (const float*)d_in[9];
  const float* U2 = (const float*)d_in[10];
  const float* b2 = (const float*)d_in[11];
  const float* s2 = (const float*)d_in[12];
  const float* Wd = (const float*)d_in[13];
  const float* bd = (const float*)d_in[14];
  float* ws = (float*)d_ws;

  gru_init_kernel<<<192, 256, 0, stream>>>(s0, s1, s2, ws);
  gru_persist<<<NB, 256, 0, stream>>>(x, W0, U0, b0, W1, U1, b1,
                                      W2, U2, b2, Wd, bd, (float*)d_out, ws);
}

// Round 2
// 35391.437 us; speedup vs baseline: 5.3561x; 5.3561x over previous
//
#include <hip/hip_runtime.h>
#include <math.h>

#define B_   32
#define INS  1000
#define TS   999           // recurrent steps computed (t = 0..998)
#define D_   128
#define U_   512
#define G3   1536
#define OUTS 100
#define NB   208           // persistent grid: 16 LX + 64 L0 + 64 L1 + 64 L2
#define NTICK 1002         // LX: T=t (0..998); layer j computes t = T-(j+1)

// ws layout (floats)
#define HBUF_OFF 0                       // [2][3][512][32]  (parity, layer, k, e)
#define HBUF_SZ  (2*3*512*32)            // 98304
#define RING_OFF HBUF_SZ                 // [4][1536][32]    mx0 ring
#define RING_SZ  (4*1536*32)             // 196608
#define BAR_OFF  (RING_OFF + RING_SZ)    // 2 x u32 barrier state

// LDS layout (floats):
//   weights at [0, 24640): L1/L2: 8 chunks * (128*24 + 8 pad) = 8*3080
//                          L0:    8 chunks * (64*24 + 8 pad)  = 8*1544
//                          LX:    [128][96] = 12288
//   part at [24640, 32320): [q][g][c][e_pad40] = 8*3*8*40 = 7680
#define W_CHK1  3080
#define W_CHK0  1544
#define PART_OFF 24640
#define SMEM_FLOATS 32320
#define PIDX2(q,g,c,e) ((((q)*3+(g))*8+(c))*40 + (e))

#define FMA24() \
  acc[0][0]=fmaf(a0.x,w0,acc[0][0]); acc[0][1]=fmaf(a0.y,w0,acc[0][1]); \
  acc[0][2]=fmaf(a0.z,w0,acc[0][2]); acc[0][3]=fmaf(a0.w,w0,acc[0][3]); \
  acc[0][4]=fmaf(a1.x,w0,acc[0][4]); acc[0][5]=fmaf(a1.y,w0,acc[0][5]); \
  acc[0][6]=fmaf(a1.z,w0,acc[0][6]); acc[0][7]=fmaf(a1.w,w0,acc[0][7]); \
  acc[1][0]=fmaf(a0.x,w1,acc[1][0]); acc[1][1]=fmaf(a0.y,w1,acc[1][1]); \
  acc[1][2]=fmaf(a0.z,w1,acc[1][2]); acc[1][3]=fmaf(a0.w,w1,acc[1][3]); \
  acc[1][4]=fmaf(a1.x,w1,acc[1][4]); acc[1][5]=fmaf(a1.y,w1,acc[1][5]); \
  acc[1][6]=fmaf(a1.z,w1,acc[1][6]); acc[1][7]=fmaf(a1.w,w1,acc[1][7]); \
  acc[2][0]=fmaf(a0.x,w2,acc[2][0]); acc[2][1]=fmaf(a0.y,w2,acc[2][1]); \
  acc[2][2]=fmaf(a0.z,w2,acc[2][2]); acc[2][3]=fmaf(a0.w,w2,acc[2][3]); \
  acc[2][4]=fmaf(a1.x,w2,acc[2][4]); acc[2][5]=fmaf(a1.y,w2,acc[2][5]); \
  acc[2][6]=fmaf(a1.z,w2,acc[2][6]); acc[2][7]=fmaf(a1.w,w2,acc[2][7]);

__global__ void gru_init_kernel(const float* __restrict__ s0,
                                const float* __restrict__ s1,
                                const float* __restrict__ s2,
                                float* __restrict__ ws) {
  int g = blockIdx.x * 256 + threadIdx.x;
  if (g < 2) { unsigned* bar = (unsigned*)(ws + BAR_OFF); bar[g] = 0u; }
  // init h(-1): hbuf[0][0]=s0, hbuf[1][1]=s1, hbuf[0][2]=s2
  for (int i = g; i < 3 * 512 * 32; i += gridDim.x * 256) {
    int which = i / (512 * 32);
    int r = i - which * (512 * 32);
    int k = r >> 5, e = r & 31;
    int par = (which == 1) ? 1 : 0;
    const float* s = (which == 0) ? s0 : ((which == 1) ? s1 : s2);
    ws[HBUF_OFF + par * 49152 + which * 16384 + k * 32 + e] = s[k];
  }
}

__device__ __forceinline__ void gbar(unsigned* bar, unsigned ep) {
  __syncthreads();
  if (threadIdx.x == 0) {
    __threadfence();
    unsigned prev = __hip_atomic_fetch_add(&bar[0], 1u, __ATOMIC_ACQ_REL,
                                           __HIP_MEMORY_SCOPE_AGENT);
    if (prev == ep * (unsigned)NB - 1u) {
      __hip_atomic_store(&bar[1], ep, __ATOMIC_RELEASE, __HIP_MEMORY_SCOPE_AGENT);
    } else {
      unsigned cur;
      do {
        __builtin_amdgcn_s_sleep(2);
        cur = __hip_atomic_load(&bar[1], __ATOMIC_ACQUIRE, __HIP_MEMORY_SCOPE_AGENT);
      } while (cur < ep);
    }
    __threadfence();
  }
  __syncthreads();
}

__global__ __launch_bounds__(256, 1) void gru_persist(
    const float* __restrict__ x,
    const float* __restrict__ W0c, const float* __restrict__ U0c, const float* __restrict__ b0c,
    const float* __restrict__ W1c, const float* __restrict__ U1c, const float* __restrict__ b1c,
    const float* __restrict__ W2c, const float* __restrict__ U2c, const float* __restrict__ b2c,
    const float* __restrict__ Wd, const float* __restrict__ bd,
    float* __restrict__ out, float* __restrict__ ws)
{
  float* hbuf = ws + HBUF_OFF;
  float* ring = ws + RING_OFF;
  unsigned* bar = (unsigned*)(ws + BAR_OFF);
  float* pred_out = out;                       // [32][100][128]
  float* hid_out  = out + B_ * OUTS * D_;      // [32][100][3][512]

  const int bid = blockIdx.x;
  const int tid = threadIdx.x;

  // roles: bid 0..15 LX, 16..79 layer0, 80..143 layer1, 144..207 layer2
  int role, rb;
  if      (bid < 16)  { role = -1; rb = bid; }
  else if (bid < 80)  { role = 0;  rb = bid - 16; }
  else if (bid < 144) { role = 1;  rb = bid - 80; }
  else                { role = 2;  rb = bid - 144; }

  __shared__ float smem[SMEM_FLOATS];     // 126.25 KiB (weights + part)
  float* part = smem + PART_OFF;

  // GEMM-phase thread mapping (layer blocks): c_l 0..7, q 0..7, eg 0..3
  const int c_l = tid & 7;
  const int q   = (tid >> 3) & 7;
  const int eg  = tid >> 6;
  // XCD-locality col swizzle
  const int cb  = (rb & 7) * 8 + (rb >> 3);
  const int c0  = cb * 8;
  // reduce/elementwise mapping
  const int rc = tid >> 5;     // col within block 0..7
  const int re = tid & 31;     // batch elem 0..31
  // LX mapping
  const int xb0 = ((rb & 7) * 2 + (rb >> 3)) * 96;  // only valid for role<0
  const int cg3 = (tid & 31) * 3;   // 3 local cols
  const int e0  = (tid >> 5) * 4;   // 4 batch elems

  const float *Wj = nullptr, *Ujp = nullptr, *bj = nullptr;
  if      (role == 0) { Ujp = U0c; bj = b0c; }
  else if (role == 1) { Wj = W1c; Ujp = U1c; bj = b1c; }
  else if (role == 2) { Wj = W2c; Ujp = U2c; bj = b2c; }

  // ---- one-time: stage this block's weight slice into LDS ----
  if (role < 0) {
    // W0 slice: cols xb0..xb0+95, layout smem[k*96 + cl]
    for (int idx = tid; idx < 128 * 96; idx += 256)
      smem[idx] = W0c[(idx / 96) * G3 + xb0 + (idx % 96)];
  } else {
    const int chunk = (role == 0) ? 64 : 128;
    const int chks  = (role == 0) ? W_CHK0 : W_CHK1;
    const int total = 8 * chunk * 24;
    for (int idx = tid; idx < total; idx += 256) {
      int qq = idx / (chunk * 24);
      int r  = idx - qq * (chunk * 24);
      int i  = r / 24;
      int cg = r - i * 24;
      int c  = cg / 3, g = cg - c * 3;
      const float* mat; int row;
      if (role == 0)      { mat = Ujp; row = qq * 64 + i; }
      else if (qq < 4)    { mat = Wj;  row = qq * 128 + i; }
      else                { mat = Ujp; row = (qq - 4) * 128 + i; }
      smem[qq * chks + (i * 8 + c) * 3 + g] = mat[row * G3 + g * 512 + c0 + c];
    }
  }
  // bias preload (constant over ticks)
  float bz = 0.f, br = 0.f, b0h = 0.f, b1h = 0.f;
  if (role >= 0) {
    const int cg2 = c0 + rc;
    bz  = bj[cg2] + bj[G3 + cg2];
    br  = bj[512 + cg2] + bj[G3 + 512 + cg2];
    b0h = bj[1024 + cg2];
    b1h = bj[G3 + 1024 + cg2];
  }
  __syncthreads();

  for (int T = 0; T < NTICK; ++T) {
    const int par_prev = (T + 1) & 1;
    const int par_cur  = T & 1;

    if (role < 0) {
      // LX: mx0(t=T) = x_t @ W0 (no bias), ring slot t&3, layout [gcol][e]
      const int t = T;
      if (t < TS) {
        float* dst = ring + (t & 3) * (G3 * 32);
        float acc[3][4];
        #pragma unroll
        for (int c = 0; c < 3; ++c)
          #pragma unroll
          for (int e = 0; e < 4; ++e) acc[c][e] = 0.f;
        const float* xbase = x + t * D_;
        #pragma unroll 2
        for (int k4 = 0; k4 < D_; k4 += 4) {
          float xs[4][4];
          #pragma unroll
          for (int e = 0; e < 4; ++e) {
            float4 v = *(const float4*)(xbase + (e0 + e) * (INS * D_) + k4);
            xs[e][0] = v.x; xs[e][1] = v.y; xs[e][2] = v.z; xs[e][3] = v.w;
          }
          #pragma unroll
          for (int kk = 0; kk < 4; ++kk) {
            const float* wp = smem + (k4 + kk) * 96 + cg3;
            float w0 = wp[0], w1 = wp[1], w2 = wp[2];
            #pragma unroll
            for (int e = 0; e < 4; ++e) {
              acc[0][e] = fmaf(xs[e][kk], w0, acc[0][e]);
              acc[1][e] = fmaf(xs[e][kk], w1, acc[1][e]);
              acc[2][e] = fmaf(xs[e][kk], w2, acc[2][e]);
            }
          }
        }
        #pragma unroll
        for (int c = 0; c < 3; ++c)
          *(float4*)(dst + (xb0 + cg3 + c) * 32 + e0) =
              make_float4(acc[c][0], acc[c][1], acc[c][2], acc[c][3]);
      }
    } else {
      const int j = role;
      const int t = T - (j + 1);
      if (t >= 0 && t < TS) {
        const float* hprev_all = hbuf + par_prev * 49152;
        float acc[3][8];
        #pragma unroll
        for (int g2 = 0; g2 < 3; ++g2)
          #pragma unroll
          for (int i2 = 0; i2 < 8; ++i2) acc[g2][i2] = 0.f;

        if (j == 0) {
          const float* A  = hprev_all + (q * 64) * 32 + eg * 8;
          const float* wp = smem + q * W_CHK0 + c_l * 3;
          #pragma unroll 4
          for (int i = 0; i < 64; ++i) {
            float4 a0 = *(const float4*)(A);
            float4 a1 = *(const float4*)(A + 4);
            float w0 = wp[0], w1 = wp[1], w2 = wp[2];
            FMA24();
            A += 32; wp += 24;
          }
        } else {
          const int kb = (q & 3) * 128;
          const float* A  = hprev_all + ((q < 4) ? (j - 1) : j) * 16384 + kb * 32 + eg * 8;
          const float* wp = smem + q * W_CHK1 + c_l * 3;
          #pragma unroll 4
          for (int i = 0; i < 128; ++i) {
            float4 a0 = *(const float4*)(A);
            float4 a1 = *(const float4*)(A + 4);
            float w0 = wp[0], w1 = wp[1], w2 = wp[2];
            FMA24();
            A += 32; wp += 24;
          }
        }
        #pragma unroll
        for (int g2 = 0; g2 < 3; ++g2) {
          *(float4*)&part[PIDX2(q, g2, c_l, eg * 8)] =
              make_float4(acc[g2][0], acc[g2][1], acc[g2][2], acc[g2][3]);
          *(float4*)&part[PIDX2(q, g2, c_l, eg * 8) + 4] =
              make_float4(acc[g2][4], acc[g2][5], acc[g2][6], acc[g2][7]);
        }
        __syncthreads();

        // reduce over q + GRU elementwise; thread <-> (rc, re)
        float gz = 0.f, gr = 0.f, xh = 0.f, hh = 0.f;
        #pragma unroll
        for (int q2 = 0; q2 < 8; ++q2) {
          gz += part[PIDX2(q2, 0, rc, re)];
          gr += part[PIDX2(q2, 1, rc, re)];
          float v = part[PIDX2(q2, 2, rc, re)];
          if (j == 0)       hh += v;
          else if (q2 < 4)  xh += v;
          else              hh += v;
        }
        const int cg2 = c0 + rc;
        float xz = 0.f, xr2 = 0.f, xhv;
        if (j == 0) {
          const float* r3 = ring + (t & 3) * (G3 * 32);
          xz  = r3[cg2 * 32 + re];
          xr2 = r3[(512 + cg2) * 32 + re];
          xhv = r3[(1024 + cg2) * 32 + re];
        } else {
          xhv = xh;
        }
        const float zi = gz + xz + bz;
        const float ri = gr + xr2 + br;
        const float z = 1.f / (1.f + expf(-zi));
        const float r = 1.f / (1.f + expf(-ri));
        const float cand = tanhf((xhv + b0h) + r * (hh + b1h));
        const float hp = hbuf[par_prev * 49152 + j * 16384 + cg2 * 32 + re];
        const float hn = z * hp + (1.f - z) * cand;
        hbuf[par_cur * 49152 + j * 16384 + cg2 * 32 + re] = hn;
        if (t >= TS - OUTS) {
          hid_out[((re * OUTS + (t - (TS - OUTS))) * 3 + j) * U_ + cg2] = hn;
        }
      }
      // inactive ticks fall through to barrier
    }
    gbar(bar, (unsigned)(T + 1));
  }

  // readout: pred[b][s][dd] = ys[b][s] @ Wd + bd   (ys = hidden[...,2,:])
  const int gt = bid * 256 + tid;
  for (int o = gt; o < B_ * OUTS * D_; o += NB * 256) {
    int b  = o / (OUTS * D_);
    int r2 = o - b * (OUTS * D_);
    int s  = r2 >> 7;
    int dd = r2 & 127;
    const float* ys = hid_out + ((b * OUTS + s) * 3 + 2) * U_;
    float acc = bd[dd];
    #pragma unroll 4
    for (int k = 0; k < U_; k += 4) {
      float4 yv = *(const float4*)(ys + k);
      acc = fmaf(yv.x, Wd[(k    ) * D_ + dd], acc);
      acc = fmaf(yv.y, Wd[(k + 1) * D_ + dd], acc);
      acc = fmaf(yv.z, Wd[(k + 2) * D_ + dd], acc);
      acc = fmaf(yv.w, Wd[(k + 3) * D_ + dd], acc);
    }
    pred_out[o] = acc;
  }
}

extern "C" void kernel_launch(void* const* d_in, const int* in_sizes, int n_in,
                              void* d_out, int out_size, void* d_ws, size_t ws_size,
                              hipStream_t stream) {
  const float* x  = (const float*)d_in[0];
  const float* W0 = (const float*)d_in[1];
  const float* U0 = (const float*)d_in[2];
  const float* b0 = (const float*)d_in[3];
  const float* s0 = (const float*)d_in[4];
  const float* W1 = (const float*)d_in[5];
  const float* U1 = (const float*)d_in[6];
  const float* b1 = (const float*)d_in[7];
  const float* s1 = (const float*)d_in[8];
  const float* W2 = (const float*)d_in[9];
  const float* U2 = (const float*)d_in[10];
  const float* b2 = (const float*)d_in[11];
  const float* s2 = (const float*)d_in[12];
  const float* Wd = (const float*)d_in[13];
  const float* bd = (const float*)d_in[14];
  float* ws = (float*)d_ws;

  gru_init_kernel<<<192, 256, 0, stream>>>(s0, s1, s2, ws);
  gru_persist<<<NB, 256, 0, stream>>>(x, W0, U0, b0, W1, U1, b1,
                                      W2, U2, b2, Wd, bd, (float*)d_out, ws);
}

// Round 3
// 15583.653 us; speedup vs baseline: 12.1641x; 2.2711x over previous
//
#include <hip/hip_runtime.h>
#include <math.h>

#define B_   32
#define INS  1000
#define TS   999           // recurrent steps computed (t = 0..998)
#define D_   128
#define U_   512
#define G3   1536
#define OUTS 100
#define NB   208           // persistent grid: 16 LX + 64 L0 + 64 L1 + 64 L2
#define NTICK 1002         // LX: T=t (0..998); layer j computes t = T-(j+1)
#define NTHR 512

// ws layout (floats)
#define HBUF_OFF 0                       // [2][3][512][32]  (parity, layer, k, e)
#define HBUF_SZ  (2*3*512*32)            // 98304
#define RING_OFF HBUF_SZ                 // [4][1536][32]    mx0 ring
#define RING_SZ  (4*1536*32)             // 196608
#define BAR_OFF  (RING_OFF + RING_SZ)    // barrier state: 1024 u32
// bar[0]=epoch flag, bar[32]=root counter, bar[64+g*32]=leaf counter g (16 leaves)

// LDS layout (floats):
//   weights at [0, 24640): L1/L2: 8 chunks * (128*24 + 8 pad) = 8*3080
//                          L0:    8 chunks * (64*24 + 8 pad)  = 8*1544
//                          LX:    [128][96] = 12288
//   part at [24640, 32320): [q][g][c][e_pad40] = 8*3*8*40 = 7680
#define W_CHK1  3080
#define W_CHK0  1544
#define PART_OFF 24640
#define SMEM_FLOATS 32320
#define PIDX2(q,g,c,e) ((((q)*3+(g))*8+(c))*40 + (e))

#define FMA12() \
  acc[0][0]=fmaf(av.x,w0,acc[0][0]); acc[0][1]=fmaf(av.y,w0,acc[0][1]); \
  acc[0][2]=fmaf(av.z,w0,acc[0][2]); acc[0][3]=fmaf(av.w,w0,acc[0][3]); \
  acc[1][0]=fmaf(av.x,w1,acc[1][0]); acc[1][1]=fmaf(av.y,w1,acc[1][1]); \
  acc[1][2]=fmaf(av.z,w1,acc[1][2]); acc[1][3]=fmaf(av.w,w1,acc[1][3]); \
  acc[2][0]=fmaf(av.x,w2,acc[2][0]); acc[2][1]=fmaf(av.y,w2,acc[2][1]); \
  acc[2][2]=fmaf(av.z,w2,acc[2][2]); acc[2][3]=fmaf(av.w,w2,acc[2][3]);

__global__ void gru_init_kernel(const float* __restrict__ s0,
                                const float* __restrict__ s1,
                                const float* __restrict__ s2,
                                float* __restrict__ ws) {
  int g = blockIdx.x * 256 + threadIdx.x;
  if (g < 1024) { unsigned* bar = (unsigned*)(ws + BAR_OFF); bar[g] = 0u; }
  // init h(-1): hbuf[0][0]=s0, hbuf[1][1]=s1, hbuf[0][2]=s2
  for (int i = g; i < 3 * 512 * 32; i += gridDim.x * 256) {
    int which = i / (512 * 32);
    int r = i - which * (512 * 32);
    int k = r >> 5, e = r & 31;
    int par = (which == 1) ? 1 : 0;
    const float* s = (which == 0) ? s0 : ((which == 1) ? s1 : s2);
    ws[HBUF_OFF + par * 49152 + which * 16384 + k * 32 + e] = s[k];
  }
}

// Tree barrier: leaf RMWs (13 per leaf, 16 leaves in parallel) -> root (16 RMWs)
// -> release flag. Spin with RELAXED loads (no per-poll cache invalidation!),
// then ONE agent acquire fence.
__device__ __forceinline__ void gbar(unsigned* bar, unsigned ep, int grp) {
  __syncthreads();
  if (threadIdx.x == 0) {
    unsigned lp = __hip_atomic_fetch_add(&bar[64 + grp * 32], 1u,
                                         __ATOMIC_ACQ_REL, __HIP_MEMORY_SCOPE_AGENT);
    if (lp == ep * 13u - 1u) {
      unsigned rp = __hip_atomic_fetch_add(&bar[32], 1u,
                                           __ATOMIC_ACQ_REL, __HIP_MEMORY_SCOPE_AGENT);
      if (rp == ep * 16u - 1u) {
        __hip_atomic_store(&bar[0], ep, __ATOMIC_RELEASE, __HIP_MEMORY_SCOPE_AGENT);
      }
    }
    while (__hip_atomic_load(&bar[0], __ATOMIC_RELAXED, __HIP_MEMORY_SCOPE_AGENT) < ep) {
      __builtin_amdgcn_s_sleep(1);
    }
    __builtin_amdgcn_fence(__ATOMIC_ACQUIRE, "agent");
  }
  __syncthreads();
}

__global__ __launch_bounds__(NTHR, 1) void gru_persist(
    const float* __restrict__ x,
    const float* __restrict__ W0c, const float* __restrict__ U0c, const float* __restrict__ b0c,
    const float* __restrict__ W1c, const float* __restrict__ U1c, const float* __restrict__ b1c,
    const float* __restrict__ W2c, const float* __restrict__ U2c, const float* __restrict__ b2c,
    const float* __restrict__ Wd, const float* __restrict__ bd,
    float* __restrict__ out, float* __restrict__ ws)
{
  float* hbuf = ws + HBUF_OFF;
  float* ring = ws + RING_OFF;
  unsigned* bar = (unsigned*)(ws + BAR_OFF);
  float* pred_out = out;                       // [32][100][128]
  float* hid_out  = out + B_ * OUTS * D_;      // [32][100][3][512]

  const int bid = blockIdx.x;
  const int tid = threadIdx.x;
  const int grp = bid & 15;                    // 208 = 16 groups x 13

  // roles: bid 0..15 LX, 16..79 layer0, 80..143 layer1, 144..207 layer2
  int role, rb;
  if      (bid < 16)  { role = -1; rb = bid; }
  else if (bid < 80)  { role = 0;  rb = bid - 16; }
  else if (bid < 144) { role = 1;  rb = bid - 80; }
  else                { role = 2;  rb = bid - 144; }

  __shared__ float smem[SMEM_FLOATS];     // 126.25 KiB (weights + part)
  float* part = smem + PART_OFF;

  // GEMM-phase thread mapping (layer blocks): c_l 0..7, q 0..7, eg 0..7 (4 elems)
  const int c_l = tid & 7;
  const int q   = (tid >> 3) & 7;
  const int eg  = tid >> 6;
  // XCD-locality col swizzle
  const int cb  = (rb & 7) * 8 + (rb >> 3);
  const int c0  = cb * 8;
  // reduce/elementwise mapping (tid < 256 only)
  const int rc = tid >> 5;     // col within block 0..7
  const int re = tid & 31;     // batch elem 0..31
  // LX mapping: 96 cols x 32 elems over 512 threads
  const int xb0 = ((rb & 7) * 2 + (rb >> 3)) * 96;  // only valid for role<0
  const int cg3 = (tid & 31) * 3;   // 3 local cols
  const int e0  = (tid >> 5) * 2;   // 2 batch elems

  const float *Wj = nullptr, *Ujp = nullptr, *bj = nullptr;
  if      (role == 0) { Ujp = U0c; bj = b0c; }
  else if (role == 1) { Wj = W1c; Ujp = U1c; bj = b1c; }
  else if (role == 2) { Wj = W2c; Ujp = U2c; bj = b2c; }

  // ---- one-time: stage this block's weight slice into LDS ----
  if (role < 0) {
    for (int idx = tid; idx < 128 * 96; idx += NTHR)
      smem[idx] = W0c[(idx / 96) * G3 + xb0 + (idx % 96)];
  } else {
    const int chunk = (role == 0) ? 64 : 128;
    const int chks  = (role == 0) ? W_CHK0 : W_CHK1;
    const int total = 8 * chunk * 24;
    for (int idx = tid; idx < total; idx += NTHR) {
      int qq = idx / (chunk * 24);
      int r  = idx - qq * (chunk * 24);
      int i  = r / 24;
      int cg = r - i * 24;
      int c  = cg / 3, g = cg - c * 3;
      const float* mat; int row;
      if (role == 0)      { mat = Ujp; row = qq * 64 + i; }
      else if (qq < 4)    { mat = Wj;  row = qq * 128 + i; }
      else                { mat = Ujp; row = (qq - 4) * 128 + i; }
      smem[qq * chks + (i * 8 + c) * 3 + g] = mat[row * G3 + g * 512 + c0 + c];
    }
  }
  // bias preload (constant over ticks)
  float bz = 0.f, br = 0.f, b0h = 0.f, b1h = 0.f;
  if (role >= 0 && tid < 256) {
    const int cg2 = c0 + rc;
    bz  = bj[cg2] + bj[G3 + cg2];
    br  = bj[512 + cg2] + bj[G3 + 512 + cg2];
    b0h = bj[1024 + cg2];
    b1h = bj[G3 + 1024 + cg2];
  }
  __syncthreads();

  for (int T = 0; T < NTICK; ++T) {
    const int par_prev = (T + 1) & 1;
    const int par_cur  = T & 1;

    if (role < 0) {
      // LX: mx0(t=T) = x_t @ W0 (no bias), ring slot t&3, layout [gcol][e]
      const int t = T;
      if (t < TS) {
        float* dst = ring + (t & 3) * (G3 * 32);
        float acc[3][2];
        #pragma unroll
        for (int c = 0; c < 3; ++c) { acc[c][0] = 0.f; acc[c][1] = 0.f; }
        const float* xr0 = x + (e0    ) * (INS * D_) + t * D_;
        const float* xr1 = x + (e0 + 1) * (INS * D_) + t * D_;
        #pragma unroll 4
        for (int k4 = 0; k4 < D_; k4 += 4) {
          float4 v0 = *(const float4*)(xr0 + k4);
          float4 v1 = *(const float4*)(xr1 + k4);
          float xs0[4] = {v0.x, v0.y, v0.z, v0.w};
          float xs1[4] = {v1.x, v1.y, v1.z, v1.w};
          #pragma unroll
          for (int kk = 0; kk < 4; ++kk) {
            const float* wp = smem + (k4 + kk) * 96 + cg3;
            float w0 = wp[0], w1 = wp[1], w2 = wp[2];
            acc[0][0] = fmaf(xs0[kk], w0, acc[0][0]);
            acc[0][1] = fmaf(xs1[kk], w0, acc[0][1]);
            acc[1][0] = fmaf(xs0[kk], w1, acc[1][0]);
            acc[1][1] = fmaf(xs1[kk], w1, acc[1][1]);
            acc[2][0] = fmaf(xs0[kk], w2, acc[2][0]);
            acc[2][1] = fmaf(xs1[kk], w2, acc[2][1]);
          }
        }
        #pragma unroll
        for (int c = 0; c < 3; ++c)
          *(float2*)(dst + (xb0 + cg3 + c) * 32 + e0) = make_float2(acc[c][0], acc[c][1]);
      }
    } else {
      const int j = role;
      const int t = T - (j + 1);
      if (t >= 0 && t < TS) {
        const float* hprev_all = hbuf + par_prev * 49152;
        float acc[3][4];
        #pragma unroll
        for (int g2 = 0; g2 < 3; ++g2)
          #pragma unroll
          for (int i2 = 0; i2 < 4; ++i2) acc[g2][i2] = 0.f;

        if (j == 0) {
          const float* A  = hprev_all + (q * 64) * 32 + eg * 4;
          const float* wp = smem + q * W_CHK0 + c_l * 3;
          #pragma unroll 8
          for (int i = 0; i < 64; ++i) {
            float4 av = *(const float4*)(A);
            float w0 = wp[0], w1 = wp[1], w2 = wp[2];
            FMA12();
            A += 32; wp += 24;
          }
        } else {
          const int kb = (q & 3) * 128;
          const float* A  = hprev_all + ((q < 4) ? (j - 1) : j) * 16384 + kb * 32 + eg * 4;
          const float* wp = smem + q * W_CHK1 + c_l * 3;
          #pragma unroll 8
          for (int i = 0; i < 128; ++i) {
            float4 av = *(const float4*)(A);
            float w0 = wp[0], w1 = wp[1], w2 = wp[2];
            FMA12();
            A += 32; wp += 24;
          }
        }
        #pragma unroll
        for (int g2 = 0; g2 < 3; ++g2) {
          *(float4*)&part[PIDX2(q, g2, c_l, eg * 4)] =
              make_float4(acc[g2][0], acc[g2][1], acc[g2][2], acc[g2][3]);
        }
        __syncthreads();

        // reduce over q + GRU elementwise; thread <-> (rc, re), tid<256
        if (tid < 256) {
          float gz = 0.f, gr = 0.f, xh = 0.f, hh = 0.f;
          #pragma unroll
          for (int q2 = 0; q2 < 8; ++q2) {
            gz += part[PIDX2(q2, 0, rc, re)];
            gr += part[PIDX2(q2, 1, rc, re)];
            float v = part[PIDX2(q2, 2, rc, re)];
            if (j == 0)       hh += v;
            else if (q2 < 4)  xh += v;
            else              hh += v;
          }
          const int cg2 = c0 + rc;
          float xz = 0.f, xr2 = 0.f, xhv;
          if (j == 0) {
            const float* r3 = ring + (t & 3) * (G3 * 32);
            xz  = r3[cg2 * 32 + re];
            xr2 = r3[(512 + cg2) * 32 + re];
            xhv = r3[(1024 + cg2) * 32 + re];
          } else {
            xhv = xh;
          }
          const float zi = gz + xz + bz;
          const float ri = gr + xr2 + br;
          const float z = 1.f / (1.f + expf(-zi));
          const float r = 1.f / (1.f + expf(-ri));
          const float cand = tanhf((xhv + b0h) + r * (hh + b1h));
          const float hp = hbuf[par_prev * 49152 + j * 16384 + cg2 * 32 + re];
          const float hn = z * hp + (1.f - z) * cand;
          hbuf[par_cur * 49152 + j * 16384 + cg2 * 32 + re] = hn;
          if (t >= TS - OUTS) {
            hid_out[((re * OUTS + (t - (TS - OUTS))) * 3 + j) * U_ + cg2] = hn;
          }
        }
      }
      // inactive ticks fall through to barrier
    }
    gbar(bar, (unsigned)(T + 1), grp);
  }

  // readout: pred[b][s][dd] = ys[b][s] @ Wd + bd   (ys = hidden[...,2,:])
  const int gt = bid * NTHR + tid;
  for (int o = gt; o < B_ * OUTS * D_; o += NB * NTHR) {
    int b  = o / (OUTS * D_);
    int r2 = o - b * (OUTS * D_);
    int s  = r2 >> 7;
    int dd = r2 & 127;
    const float* ys = hid_out + ((b * OUTS + s) * 3 + 2) * U_;
    float acc = bd[dd];
    #pragma unroll 4
    for (int k = 0; k < U_; k += 4) {
      float4 yv = *(const float4*)(ys + k);
      acc = fmaf(yv.x, Wd[(k    ) * D_ + dd], acc);
      acc = fmaf(yv.y, Wd[(k + 1) * D_ + dd], acc);
      acc = fmaf(yv.z, Wd[(k + 2) * D_ + dd], acc);
      acc = fmaf(yv.w, Wd[(k + 3) * D_ + dd], acc);
    }
    pred_out[o] = acc;
  }
}

extern "C" void kernel_launch(void* const* d_in, const int* in_sizes, int n_in,
                              void* d_out, int out_size, void* d_ws, size_t ws_size,
                              hipStream_t stream) {
  const float* x  = (const float*)d_in[0];
  const float* W0 = (const float*)d_in[1];
  const float* U0 = (const float*)d_in[2];
  const float* b0 = (const float*)d_in[3];
  const float* s0 = (const float*)d_in[4];
  const float* W1 = (const float*)d_in[5];
  const float* U1 = (const float*)d_in[6];
  const float* b1 = (const float*)d_in[7];
  const float* s1 = (const float*)d_in[8];
  const float* W2 = (const float*)d_in[9];
  const float* U2 = (const float*)d_in[10];
  const float* b2 = (const float*)d_in[11];
  const float* s2 = (const float*)d_in[12];
  const float* Wd = (const float*)d_in[13];
  const float* bd = (const float*)d_in[14];
  float* ws = (float*)d_ws;

  gru_init_kernel<<<192, 256, 0, stream>>>(s0, s1, s2, ws);
  gru_persist<<<NB, NTHR, 0, stream>>>(x, W0, U0, b0, W1, U1, b1,
                                       W2, U2, b2, Wd, bd, (float*)d_out, ws);
}